// Round 1
// baseline (1070.893 us; speedup 1.0000x reference)
//
#include <hip/hip_runtime.h>

#define N_NODES 100000
#define N_EDGES 1250000
#define D 64

// agg[dst[e]][dim] += h[src[e]][dim]; one thread per (edge, dim).
// 64 lanes of a wave = one edge: src/dst loads wave-uniform, row gather and
// atomicAdd both coalesced 256B.
__global__ void scatter_add_kernel(const float* __restrict__ h,
                                   const int* __restrict__ src,
                                   const int* __restrict__ dst,
                                   float* __restrict__ agg) {
    long long idx = (long long)blockIdx.x * blockDim.x + threadIdx.x;
    int e   = (int)(idx >> 6);
    int dim = (int)(idx & 63);
    if (e < N_EDGES) {
        int s = src[e];
        int t = dst[e];
        atomicAdd(&agg[(long long)t * D + dim], h[(long long)s * D + dim]);
    }
}

// out[n][j] = b1[j] + sum_k agg[n][k] * W1[j][k]
// W1 staged in LDS transposed (Ws[k][j]) so lanes (varying j) read
// consecutive addresses -> conflict-free (2 lanes/bank is free on gfx950).
__global__ void linear_kernel(const float* __restrict__ agg,
                              const float* __restrict__ W1,
                              const float* __restrict__ b1,
                              float* __restrict__ out) {
    __shared__ float Ws[D][D];  // Ws[k][j] = W1[j*D + k]
    int tid = threadIdx.x;  // 256 threads
    for (int i = tid; i < D * D; i += 256) {
        int k = i >> 6, j = i & 63;
        Ws[k][j] = W1[j * D + k];   // W1 is tiny; uncoalesced read is cached
    }
    __syncthreads();

    int node = blockIdx.x * 4 + (tid >> 6);
    int j    = tid & 63;
    if (node < N_NODES) {
        const float* row = agg + (long long)node * D;  // wave-uniform base
        float acc = b1[j];
#pragma unroll
        for (int k = 0; k < D; ++k) {
            acc += row[k] * Ws[k][j];  // row[k] broadcast, Ws conflict-free
        }
        out[(long long)node * D + j] = acc;
    }
}

extern "C" void kernel_launch(void* const* d_in, const int* in_sizes, int n_in,
                              void* d_out, int out_size, void* d_ws, size_t ws_size,
                              hipStream_t stream) {
    const float* x    = (const float*)d_in[0];          // [N, D]
    const int*   edge = (const int*)d_in[1];            // [2, E]: src then dst
    const float* W1   = (const float*)d_in[2];          // [D, D]
    const float* b1   = (const float*)d_in[3];          // [D]

    const int* src = edge;
    const int* dst = edge + N_EDGES;

    float* out = (float*)d_out;                 // first output:  [N, D]
    float* hid = (float*)d_out + (long long)N_NODES * D;  // second output: [N, D]

    float* agg = (float*)d_ws;                  // [N, D] scratch
    size_t agg_bytes = (size_t)N_NODES * D * sizeof(float);

    const int scatter_threads = 256;
    const long long scatter_work = (long long)N_EDGES * D;
    const int scatter_blocks = (int)((scatter_work + scatter_threads - 1) / scatter_threads);
    const int linear_blocks = (N_NODES + 3) / 4;

    // Layer 1: agg = segsum(x), hid = agg @ W1^T + b1
    hipMemsetAsync(agg, 0, agg_bytes, stream);
    scatter_add_kernel<<<scatter_blocks, scatter_threads, 0, stream>>>(x, src, dst, agg);
    linear_kernel<<<linear_blocks, 256, 0, stream>>>(agg, W1, b1, hid);

    // Layer 2: agg = segsum(hid), out = agg @ W1^T + b1
    hipMemsetAsync(agg, 0, agg_bytes, stream);
    scatter_add_kernel<<<scatter_blocks, scatter_threads, 0, stream>>>(hid, src, dst, agg);
    linear_kernel<<<linear_blocks, 256, 0, stream>>>(agg, W1, b1, out);
}

// Round 2
// 520.385 us; speedup vs baseline: 2.0579x; 2.0579x over previous
//
#include <hip/hip_runtime.h>

#define N_NODES 100000
#define N_EDGES 1250000
#define D 64

typedef long long ll;

// ---------- CSR build: counting sort of edges by dst ----------

__global__ void hist_kernel(const int* __restrict__ dst, int* __restrict__ cnt) {
    int e = blockIdx.x * 256 + threadIdx.x;
    if (e < N_EDGES) atomicAdd(&cnt[dst[e]], 1);
}

// per-block (256-elem) exclusive scan of cnt in place; block totals to bsum
__global__ void scanA_kernel(int* __restrict__ cnt, int* __restrict__ bsum) {
    __shared__ int s[256];
    int tid = threadIdx.x, gid = blockIdx.x * 256 + tid;
    int x = (gid < N_NODES) ? cnt[gid] : 0;
    s[tid] = x;
    __syncthreads();
    for (int off = 1; off < 256; off <<= 1) {
        int v = (tid >= off) ? s[tid - off] : 0;
        __syncthreads();
        s[tid] += v;
        __syncthreads();
    }
    if (gid < N_NODES) cnt[gid] = s[tid] - x;   // exclusive within block
    if (tid == 255) bsum[blockIdx.x] = s[255];  // block total
}

// single-block exclusive scan of the nb block totals
__global__ void scanB_kernel(const int* __restrict__ bsum, int* __restrict__ boff, int nb) {
    __shared__ int s[512];
    int tid = threadIdx.x;
    int x = (tid < nb) ? bsum[tid] : 0;
    s[tid] = x;
    __syncthreads();
    for (int off = 1; off < 512; off <<= 1) {
        int v = (tid >= off) ? s[tid - off] : 0;
        __syncthreads();
        s[tid] += v;
        __syncthreads();
    }
    if (tid < nb) boff[tid] = s[tid] - x;
}

// add block offsets -> cnt becomes global exclusive prefix (CSR offsets);
// also duplicate into cursor for the reorder pass
__global__ void scanC_kernel(int* __restrict__ cnt, const int* __restrict__ boff,
                             int* __restrict__ cursor) {
    int gid = blockIdx.x * 256 + threadIdx.x;
    if (gid < N_NODES) {
        int v = cnt[gid] + boff[blockIdx.x];
        cnt[gid] = v;
        cursor[gid] = v;
    }
}

__global__ void reorder_kernel(const int* __restrict__ src, const int* __restrict__ dst,
                               int* __restrict__ cursor, int* __restrict__ srt) {
    int e = blockIdx.x * 256 + threadIdx.x;
    if (e < N_EDGES) {
        int d = dst[e];
        int p = atomicAdd(&cursor[d], 1);
        srt[p] = src[e];
    }
}

// ---------- pull aggregation: one wave per node, lane = dim, no atomics ----------

__global__ __launch_bounds__(256) void pull_kernel(const float* __restrict__ h,
                                                   const int* __restrict__ offs,
                                                   const int* __restrict__ srt,
                                                   float* __restrict__ agg) {
    ll idx = (ll)blockIdx.x * 256 + threadIdx.x;
    int n = (int)(idx >> 6);
    int j = (int)(idx & 63);
    if (n >= N_NODES) return;
    int beg = offs[n];
    int end = (n == N_NODES - 1) ? N_EDGES : offs[n + 1];
    float acc = 0.f;
    int e = beg;
    if (e < end) {
        int s = srt[e];  // wave-broadcast load
        for (;;) {
            int nxt = 0;
            bool more = (e + 1 < end);
            if (more) nxt = srt[e + 1];      // prefetch next src id
            acc += h[(ll)s * D + j];          // coalesced 256B row gather
            if (!more) break;
            s = nxt;
            ++e;
        }
    }
    agg[(ll)n * D + j] = acc;
}

// ---------- linear: out[n][j] = b1[j] + sum_k agg[n][k] * W1[j][k] ----------
// thread = node; row in registers (16 float4 coalesced loads); W1 transposed in
// LDS with stride 68 (16B-aligned float4 rows, conflict-free broadcast reads);
// 64 fp32 accumulators. NOTE: no __restrict__ on agg/out — called in-place.
#define LB 128
__global__ __launch_bounds__(LB, 1) void linear_kernel(const float* agg,
                                                       const float* __restrict__ W1,
                                                       const float* __restrict__ b1,
                                                       float* out) {
    __shared__ __align__(16) float Ws[64 * 68];  // Ws[k*68+j] = W1[j*64+k]
    int tid = threadIdx.x;
    for (int i = tid; i < D * D; i += LB) {
        int j = i >> 6, k = i & 63;
        Ws[k * 68 + j] = W1[i];  // coalesced read of W1
    }
    __syncthreads();

    int n = blockIdx.x * LB + tid;
    if (n >= N_NODES) return;

    // load full row into registers BEFORE any store (in-place safety)
    float4 r[16];
    const float4* row4 = (const float4*)(agg + (ll)n * D);
#pragma unroll
    for (int k4 = 0; k4 < 16; ++k4) r[k4] = row4[k4];

    float acc[64];
#pragma unroll
    for (int j4 = 0; j4 < 16; ++j4) {
        float4 b = ((const float4*)b1)[j4];  // broadcast, L2-hot
        acc[4 * j4 + 0] = b.x; acc[4 * j4 + 1] = b.y;
        acc[4 * j4 + 2] = b.z; acc[4 * j4 + 3] = b.w;
    }

#pragma unroll
    for (int k4 = 0; k4 < 16; ++k4) {
#pragma unroll
        for (int dk = 0; dk < 4; ++dk) {
            int k = 4 * k4 + dk;
            float rk = (dk == 0) ? r[k4].x : (dk == 1) ? r[k4].y : (dk == 2) ? r[k4].z : r[k4].w;
            const float4* wr = (const float4*)&Ws[k * 68];  // 16B-aligned (272B stride)
#pragma unroll
            for (int j4 = 0; j4 < 16; ++j4) {
                float4 w = wr[j4];  // wave-uniform broadcast ds_read_b128
                acc[4 * j4 + 0] += rk * w.x;
                acc[4 * j4 + 1] += rk * w.y;
                acc[4 * j4 + 2] += rk * w.z;
                acc[4 * j4 + 3] += rk * w.w;
            }
        }
    }

    float4* o4 = (float4*)(out + (ll)n * D);
#pragma unroll
    for (int j4 = 0; j4 < 16; ++j4) {
        float4 v;
        v.x = acc[4 * j4 + 0]; v.y = acc[4 * j4 + 1];
        v.z = acc[4 * j4 + 2]; v.w = acc[4 * j4 + 3];
        o4[j4] = v;
    }
}

extern "C" void kernel_launch(void* const* d_in, const int* in_sizes, int n_in,
                              void* d_out, int out_size, void* d_ws, size_t ws_size,
                              hipStream_t stream) {
    const float* x  = (const float*)d_in[0];   // [N, D]
    const int* edge = (const int*)d_in[1];     // [2, E]: src row then dst row
    const float* W1 = (const float*)d_in[2];   // [D, D]
    const float* b1 = (const float*)d_in[3];   // [D]

    const int* src = edge;
    const int* dst = edge + N_EDGES;

    float* out = (float*)d_out;                          // output 0: [N, D]
    float* hid = (float*)d_out + (ll)N_NODES * D;        // output 1: [N, D]

    // workspace layout (CSR only; agg lives in d_out's out-half as scratch)
    char* ws = (char*)d_ws;
    int* cnt    = (int*)ws;                         ws += ((size_t)N_NODES * 4 + 255) & ~255ull;  // -> offsets
    int* cursor = (int*)ws;                         ws += ((size_t)N_NODES * 4 + 255) & ~255ull;
    int* bsum   = (int*)ws;                         ws += 4096;
    int* boff   = (int*)ws;                         ws += 4096;
    int* srt    = (int*)ws;                         // [E] src ids sorted by dst

    const int nbA = (N_NODES + 255) / 256;          // 391
    const int nbE = (N_EDGES + 255) / 256;          // 4883
    const int nbPull = (int)(((ll)N_NODES * 64 + 255) / 256);  // 25000
    const int nbLin = (N_NODES + LB - 1) / LB;      // 782

    // ---- build CSR (once; reused by both layers) ----
    hipMemsetAsync(cnt, 0, (size_t)N_NODES * 4, stream);
    hist_kernel<<<nbE, 256, 0, stream>>>(dst, cnt);
    scanA_kernel<<<nbA, 256, 0, stream>>>(cnt, bsum);
    scanB_kernel<<<1, 512, 0, stream>>>(bsum, boff, nbA);
    scanC_kernel<<<nbA, 256, 0, stream>>>(cnt, boff, cursor);
    reorder_kernel<<<nbE, 256, 0, stream>>>(src, dst, cursor, srt);

    // ---- layer 1: agg1 (scratch in out-half) -> hid ----
    pull_kernel<<<nbPull, 256, 0, stream>>>(x, cnt, srt, out);
    linear_kernel<<<nbLin, LB, 0, stream>>>(out, W1, b1, hid);

    // ---- layer 2: agg2 (scratch in out-half) -> out (in place) ----
    pull_kernel<<<nbPull, 256, 0, stream>>>(hid, cnt, srt, out);
    linear_kernel<<<nbLin, LB, 0, stream>>>(out, W1, b1, out);
}

// Round 3
// 312.992 us; speedup vs baseline: 3.4215x; 1.6626x over previous
//
#include <hip/hip_runtime.h>

#define N_NODES 100000
#define N_EDGES 1250000
#define D 64

typedef long long ll;

// ---------- CSR build: counting sort of edges by dst ----------

// histogram + per-edge rank (rank = old count, from atomicAdd return)
__global__ void hist_kernel(const int* __restrict__ dst, int* __restrict__ cnt,
                            int* __restrict__ rank) {
    int e = blockIdx.x * 256 + threadIdx.x;
    if (e < N_EDGES) rank[e] = atomicAdd(&cnt[dst[e]], 1);
}

// per-block (256-elem) exclusive scan of cnt in place; block totals to bsum
__global__ void scanA_kernel(int* __restrict__ cnt, int* __restrict__ bsum) {
    __shared__ int s[256];
    int tid = threadIdx.x, gid = blockIdx.x * 256 + tid;
    int x = (gid < N_NODES) ? cnt[gid] : 0;
    s[tid] = x;
    __syncthreads();
    for (int off = 1; off < 256; off <<= 1) {
        int v = (tid >= off) ? s[tid - off] : 0;
        __syncthreads();
        s[tid] += v;
        __syncthreads();
    }
    if (gid < N_NODES) cnt[gid] = s[tid] - x;   // exclusive within block
    if (tid == 255) bsum[blockIdx.x] = s[255];  // block total
}

// single-block exclusive scan of the nb block totals
__global__ void scanB_kernel(const int* __restrict__ bsum, int* __restrict__ boff, int nb) {
    __shared__ int s[512];
    int tid = threadIdx.x;
    int x = (tid < nb) ? bsum[tid] : 0;
    s[tid] = x;
    __syncthreads();
    for (int off = 1; off < 512; off <<= 1) {
        int v = (tid >= off) ? s[tid - off] : 0;
        __syncthreads();
        s[tid] += v;
        __syncthreads();
    }
    if (tid < nb) boff[tid] = s[tid] - x;
}

// add block offsets -> cnt becomes global exclusive prefix (CSR offsets)
__global__ void scanC_kernel(int* __restrict__ cnt, const int* __restrict__ boff) {
    int gid = blockIdx.x * 256 + threadIdx.x;
    if (gid < N_NODES) cnt[gid] += boff[blockIdx.x];
}

// pure scatter (no atomics): rank computed in hist
__global__ void reorder_kernel(const int* __restrict__ src, const int* __restrict__ dst,
                               const int* __restrict__ offs, const int* __restrict__ rank,
                               int* __restrict__ srt) {
    int e = blockIdx.x * 256 + threadIdx.x;
    if (e < N_EDGES) {
        srt[offs[dst[e]] + rank[e]] = src[e];
    }
}

// ---------- fused pull + linear ----------
// One wave per node (grid-stride). Lane j accumulates agg[n][j] with an
// 8-wide predicated gather batch (8 loads in flight). Then the row round-trips
// through a per-wave LDS buffer (wave-synchronous, no barrier) and is consumed
// as broadcast float4 against W1 rows held in 64 VGPRs/lane:
//   out[n][j] = b1[j] + sum_k row[k] * W1[j*64+k]
#define NBLK 1024
__global__ __launch_bounds__(256) void fused_layer(const float* __restrict__ h,
                                                   const int* __restrict__ offs,
                                                   const int* __restrict__ srt,
                                                   const float* __restrict__ W1,
                                                   const float* __restrict__ b1,
                                                   float* __restrict__ out) {
    __shared__ __align__(16) float rowbuf[4][64];
    const int tid  = threadIdx.x;
    const int lane = tid & 63;
    const int wid  = tid >> 6;
    const int gw   = blockIdx.x * 4 + wid;   // global wave id
    const int GW   = NBLK * 4;               // total waves

    // W1 row `lane` in registers: Wreg[i] = W1[lane*64 + 4i .. +4)
    float4 Wreg[16];
    const float4* wrow = (const float4*)(W1 + lane * D);
#pragma unroll
    for (int i = 0; i < 16; ++i) Wreg[i] = wrow[i];
    const float bj = b1[lane];

    for (int n = gw; n < N_NODES; n += GW) {
        const int beg = offs[n];
        const int end = (n == N_NODES - 1) ? N_EDGES : offs[n + 1];

        float a0 = 0.f, a1 = 0.f, a2 = 0.f, a3 = 0.f;
        for (int e = beg; e < end; e += 8) {
            // clamp keeps OOB slots inside srt[]; predicate zeroes their add
            int e1 = min(e + 1, end - 1), e2 = min(e + 2, end - 1);
            int e3 = min(e + 3, end - 1), e4 = min(e + 4, end - 1);
            int e5 = min(e + 5, end - 1), e6 = min(e + 6, end - 1);
            int e7 = min(e + 7, end - 1);
            int s0 = srt[e],  s1 = srt[e1], s2 = srt[e2], s3 = srt[e3];
            int s4 = srt[e4], s5 = srt[e5], s6 = srt[e6], s7 = srt[e7];
            float g0 = h[(ll)s0 * D + lane];
            float g1 = h[(ll)s1 * D + lane];
            float g2 = h[(ll)s2 * D + lane];
            float g3 = h[(ll)s3 * D + lane];
            float g4 = h[(ll)s4 * D + lane];
            float g5 = h[(ll)s5 * D + lane];
            float g6 = h[(ll)s6 * D + lane];
            float g7 = h[(ll)s7 * D + lane];
            a0 += g0;
            a1 += (e + 1 < end) ? g1 : 0.f;
            a2 += (e + 2 < end) ? g2 : 0.f;
            a3 += (e + 3 < end) ? g3 : 0.f;
            a0 += (e + 4 < end) ? g4 : 0.f;
            a1 += (e + 5 < end) ? g5 : 0.f;
            a2 += (e + 6 < end) ? g6 : 0.f;
            a3 += (e + 7 < end) ? g7 : 0.f;
        }
        const float acc = (a0 + a1) + (a2 + a3);

        // wave-synchronous LDS transpose: write lane value, read back as
        // broadcast float4 (same wave; compiler orders aliasing DS ops)
        rowbuf[wid][lane] = acc;
        float o = bj;
        const float4* rb = (const float4*)rowbuf[wid];
#pragma unroll
        for (int k4 = 0; k4 < 16; ++k4) {
            float4 r = rb[k4];     // broadcast ds_read_b128
            o += r.x * Wreg[k4].x + r.y * Wreg[k4].y
               + r.z * Wreg[k4].z + r.w * Wreg[k4].w;
        }
        out[(ll)n * D + lane] = o;
    }
}

extern "C" void kernel_launch(void* const* d_in, const int* in_sizes, int n_in,
                              void* d_out, int out_size, void* d_ws, size_t ws_size,
                              hipStream_t stream) {
    const float* x  = (const float*)d_in[0];   // [N, D]
    const int* edge = (const int*)d_in[1];     // [2, E]: src row then dst row
    const float* W1 = (const float*)d_in[2];   // [D, D]
    const float* b1 = (const float*)d_in[3];   // [D]

    const int* src = edge;
    const int* dst = edge + N_EDGES;

    float* out = (float*)d_out;                    // output 0: [N, D]
    float* hid = (float*)d_out + (ll)N_NODES * D;  // output 1: [N, D]

    // workspace layout (~10.5 MB)
    char* ws = (char*)d_ws;
    int* cnt  = (int*)ws;  ws += ((size_t)N_NODES * 4 + 255) & ~255ull;  // -> CSR offsets
    int* bsum = (int*)ws;  ws += 4096;
    int* boff = (int*)ws;  ws += 4096;
    int* rank = (int*)ws;  ws += (size_t)N_EDGES * 4;   // per-edge rank within dst
    int* srt  = (int*)ws;                               // [E] src ids sorted by dst

    const int nbA = (N_NODES + 255) / 256;   // 391
    const int nbE = (N_EDGES + 255) / 256;   // 4883

    // ---- build CSR (once; reused by both layers) ----
    hipMemsetAsync(cnt, 0, (size_t)N_NODES * 4, stream);
    hist_kernel<<<nbE, 256, 0, stream>>>(dst, cnt, rank);
    scanA_kernel<<<nbA, 256, 0, stream>>>(cnt, bsum);
    scanB_kernel<<<1, 512, 0, stream>>>(bsum, boff, nbA);
    scanC_kernel<<<nbA, 256, 0, stream>>>(cnt, boff);
    reorder_kernel<<<nbE, 256, 0, stream>>>(src, dst, cnt, rank, srt);

    // ---- layer 1: hid = segsum(x) @ W1^T + b1 ----
    fused_layer<<<NBLK, 256, 0, stream>>>(x, cnt, srt, W1, b1, hid);
    // ---- layer 2: out = segsum(hid) @ W1^T + b1 ----
    fused_layer<<<NBLK, 256, 0, stream>>>(hid, cnt, srt, W1, b1, out);
}